// Round 3
// baseline (73.892 us; speedup 1.0000x reference)
//
#include <hip/hip_runtime.h>
#include <math.h>

#define D 128
#define DEG 64           // CSR slot capacity per node (mean degree 32, P(any overflow)~2e-5)
#define CPAD 16          // cnt padding: one counter per 64B line (kills same-line atomic serialization)

typedef __attribute__((ext_vector_type(8))) short bf8;
typedef __attribute__((ext_vector_type(4))) float f4;

__device__ __forceinline__ unsigned hash_u32(unsigned x){
  x ^= x >> 16; x *= 0x7feb352du; x ^= x >> 15; x *= 0x846ca68bu; x ^= x >> 16;
  return x;
}
__device__ __forceinline__ unsigned f2bfbits(float f){
  unsigned u = __float_as_uint(f);
  return (u + 0x7fffu + ((u >> 16) & 1u)) >> 16;   // RNE bf16
}
__device__ __forceinline__ float bflo(unsigned u){ return __uint_as_float(u << 16); }
__device__ __forceinline__ float bfhi(unsigned u){ return __uint_as_float(u & 0xffff0000u); }
__device__ __forceinline__ uint4 pack8(float4 v0, float4 v1){
  uint4 o;
  o.x = f2bfbits(v0.x) | (f2bfbits(v0.y) << 16);
  o.y = f2bfbits(v0.z) | (f2bfbits(v0.w) << 16);
  o.z = f2bfbits(v1.x) | (f2bfbits(v1.y) << 16);
  o.w = f2bfbits(v1.z) | (f2bfbits(v1.w) << 16);
  return o;
}

// XCD-aware type partition: XCDs 0-3 take type-0 jobs, XCDs 4-7 type-1.
// Bijective remap; relies only on blockIdx%8 round-robin dispatch (perf heuristic).
__device__ __forceinline__ int xcd_remap(int bid, int jobs_per_type){
  if (jobs_per_type & 3) return bid;               // fallback: identity
  const int xcd = bid & 7, slot = bid >> 3;
  const int q = jobs_per_type >> 2;                // jobs per XCD within a type
  return (xcd >> 2) * jobs_per_type + (xcd & 3) * q + slot;
}

// ---- K1: zero padded cnt (1MB) + out, convert W once (64KB) ---------------
__global__ __launch_bounds__(256)
void prep_kernel(const float* __restrict__ Wa, const float* __restrict__ Wb,
                 ushort* __restrict__ W16a, ushort* __restrict__ W16b,
                 int* __restrict__ cnt, float* __restrict__ out0, int N){
  const int tid = blockIdx.x * 256 + threadIdx.x;
  const int ncnt4 = (2 * N * CPAD) / 4;           // 65536 uint4 = 1MB
  if (tid < ncnt4) ((uint4*)cnt)[tid] = uint4{0u, 0u, 0u, 0u};
  if (tid < 2 * (D * D / 8)){                     // 4096 threads convert both W
    const int ty = tid >= D * D / 8;
    const int k = tid - (ty ? D * D / 8 : 0);
    const float* __restrict__ src = ty ? Wb : Wa;
    ushort* __restrict__ dst = ty ? W16b : W16a;
    const float4 v0 = *(const float4*)(src + k * 8);
    const float4 v1 = *(const float4*)(src + k * 8 + 4);
    *(uint4*)(dst + k * 8) = pack8(v0, v1);
  }
  if (tid == 0) *out0 = 0.0f;
}

// ---- K2: linear (fp32 x -> LDS bf16 tiles -> MFMA, emits x16) + scatter ---
__global__ __launch_bounds__(256)
void linear_scatter(const float* __restrict__ xa, const float* __restrict__ xb,
                    const ushort* __restrict__ W16a, const ushort* __restrict__ W16b,
                    const float* __restrict__ ba, const float* __restrict__ bb,
                    ushort* __restrict__ x16a, ushort* __restrict__ x16b,
                    ushort* __restrict__ oa, ushort* __restrict__ ob,
                    const int* __restrict__ e_ba, const int* __restrict__ e_ab,
                    int* __restrict__ cnt, int* __restrict__ csr,
                    int E, int N){
  const int LB = 2 * (N >> 6);                   // 256 linear blocks (LB%8==0)
  __shared__ alignas(16) ushort As[4][16 * 128]; // 16KB (scatter blocks unaffected: 10>8 blocks/CU)

  if ((int)blockIdx.x < LB){
    // ---------------- ctx0 = bf16(x @ W^T + b) via MFMA ----------------
    const int nb64 = N >> 6;
    const int jid = xcd_remap((int)blockIdx.x, nb64);
    const int type = jid >= nb64;
    const int r0 = (jid - (type ? nb64 : 0)) << 6;
    const float* __restrict__ x = type ? xb : xa;
    const ushort* __restrict__ W16 = type ? W16b : W16a;
    const float* __restrict__ bias = type ? bb : ba;
    ushort* __restrict__ x16 = type ? x16b : x16a;
    ushort* __restrict__ out = type ? ob : oa;
    const int t = threadIdx.x, w = t >> 6, l = t & 63;

    // stage this wave's 16 rows: fp32 -> bf16 into LDS + coalesced x16 emit
    #pragma unroll
    for (int i = 0; i < 4; i++){
      const int cid = i * 64 + l;
      const int row = cid >> 4, kq = cid & 15;
      const size_t gr = (size_t)(r0 + w * 16 + row);
      const float4 v0 = *(const float4*)(x + (gr << 7) + (kq << 3));
      const float4 v1 = *(const float4*)(x + (gr << 7) + (kq << 3) + 4);
      const uint4 o = pack8(v0, v1);
      *(uint4*)&As[w][(row << 7) + ((kq ^ (row & 7)) << 3)] = o;
      *(uint4*)(x16 + (gr << 7) + (kq << 3)) = o;  // 1KB/instr coalesced
    }
    __syncthreads();

    const int rloc = l & 15, kg = l >> 4;
    bf8 af[4];
    #pragma unroll
    for (int ks = 0; ks < 4; ks++){
      const int kq = ks * 4 + kg;
      af[ks] = *(const bf8*)&As[w][(rloc << 7) + ((kq ^ (rloc & 7)) << 3)];
    }
    #pragma unroll
    for (int ct = 0; ct < 8; ct++){
      const int col = ct * 16 + rloc;
      const ushort* __restrict__ wr = W16 + ((size_t)col << 7);  // L2/L1-hot 32KB
      f4 acc = {0.f, 0.f, 0.f, 0.f};
      #pragma unroll
      for (int ks = 0; ks < 4; ks++){
        const bf8 bfr = *(const bf8*)(wr + ks * 32 + kg * 8);
        acc = __builtin_amdgcn_mfma_f32_16x16x32_bf16(af[ks], bfr, acc, 0, 0, 0);
      }
      const float bv = bias[col];
      #pragma unroll
      for (int r = 0; r < 4; r++){
        const int row = r0 + w * 16 + kg * 4 + r;
        out[((size_t)row << 7) + col] = (ushort)f2bfbits(acc[r] + bv);
      }
    }
  } else {
    // ---------------- one-pass CSR slot scatter (1 edge/thread) --------
    const int bid2 = (int)blockIdx.x - LB;       // 0..2047
    const int half = 1024;
    const int jid2 = xcd_remap(bid2, half);      // direction-partitioned across XCD halves
    const bool sb = jid2 >= half;
    const int* e = sb ? e_ab : e_ba;
    const int base = sb ? N : 0;
    const int b0 = sb ? jid2 - half : jid2;
    for (int i = b0 * 256 + (int)threadIdx.x; i < E; i += half * 256){
      const int src = e[i];
      const int dst = e[i + E] + base;
      const int p = atomicAdd(&cnt[(size_t)dst * CPAD], 1);  // 1 counter/line
      if (p < DEG) csr[(size_t)dst * DEG + p] = src;
    }
  }
}

// ---- K3: fused gather-mean + contrastive loss -----------------------------
__global__ __launch_bounds__(256)
void loss_fused(const ushort* __restrict__ xa, const ushort* __restrict__ xb,
                const ushort* __restrict__ ctx0a, const ushort* __restrict__ ctx0b,
                const int* __restrict__ cnt, const int* __restrict__ csr,
                float* __restrict__ out, int n){
  const int nb = n >> 4;                          // 512 jobs per type
  const int jid = xcd_remap((int)blockIdx.x, nb); // XCDs 0-3: type 0, XCDs 4-7: type 1
  const int type = jid >= nb;
  const int r0 = (jid - (type ? nb : 0)) << 4;
  const ushort* __restrict__ x    = type ? xb : xa;
  const ushort* __restrict__ feat = type ? ctx0a : ctx0b;  // src-side features
  const int nodebase = type ? n : 0;
  const int t = threadIdx.x, w = t >> 6, l = t & 63;
  const int sg = l >> 4, q = l & 15;

  __shared__ alignas(16) ushort A[16 * 128];      // 4KB ctx rows, swizzled
  __shared__ float lpos[16];
  __shared__ float2 part[4][16];

  const unsigned h = hash_u32((unsigned)jid * 2654435761u + 0x9E3779B9u);
  const unsigned bo = h & 8191u;
  const unsigned aa = (((h >> 13) & 4095u) << 1) | 1u;   // odd -> distinct mod 8192

  { // ---- phase 1: gather-mean for node row = w*4+sg (static-unrolled) ----
    const int row = w * 4 + sg;
    const int node = nodebase + r0 + row;
    const int c = min(cnt[(size_t)node * CPAD], DEG);
    const size_t sbase = (size_t)node * DEG;
    int sl0 = csr[sbase + q];
    int sl1 = csr[sbase + 16 + q];
    int sl2 = csr[sbase + 32 + q];
    int sl3 = csr[sbase + 48 + q];

    float a0=0.f,a1=0.f,a2=0.f,a3=0.f,a4=0.f,a5=0.f,a6=0.f,a7=0.f;
    const int lbase = l & 48;
    #define GMEAN_CHUNK(SL, J)                                                 \
    if (c > (J)*16){                                                           \
      _Pragma("unroll")                                                        \
      for (int i = 0; i < 16; i++){                                            \
        const int raw = __shfl((SL), lbase | i, 64);                           \
        const bool ok = (J)*16 + i < c;                                        \
        const int src = ok ? raw : 0;                                          \
        const float wt = ok ? 1.0f : 0.0f;                                     \
        const uint4 v = *(const uint4*)(feat + ((size_t)src << 7) + (q << 3)); \
        a0 += wt*bflo(v.x); a1 += wt*bfhi(v.x); a2 += wt*bflo(v.y); a3 += wt*bfhi(v.y); \
        a4 += wt*bflo(v.z); a5 += wt*bfhi(v.z); a6 += wt*bflo(v.w); a7 += wt*bfhi(v.w); \
      }                                                                        \
    }
    GMEAN_CHUNK(sl0, 0) GMEAN_CHUNK(sl1, 1) GMEAN_CHUNK(sl2, 2) GMEAN_CHUNK(sl3, 3)
    #undef GMEAN_CHUNK

    const float inv = 1.0f / (float)(c > 1 ? c : 1);
    uint4 o;
    o.x = f2bfbits(a0*inv) | (f2bfbits(a1*inv) << 16);
    o.y = f2bfbits(a2*inv) | (f2bfbits(a3*inv) << 16);
    o.z = f2bfbits(a4*inv) | (f2bfbits(a5*inv) << 16);
    o.w = f2bfbits(a6*inv) | (f2bfbits(a7*inv) << 16);
    *(uint4*)&A[(row << 7) + ((q ^ (row & 7)) << 3)] = o;
  }
  __syncthreads();

  // ---- phase 2: MFMA tiles with direct-global B, online LSE ----
  const int nloc = l & 15, kg = l >> 4;
  bf8 af[4];
  #pragma unroll
  for (int ks = 0; ks < 4; ks++){
    const int kq = ks * 4 + kg;
    af[ks] = *(const bf8*)&A[(nloc << 7) + ((kq ^ (nloc & 7)) << 3)];
  }

  float M0=-1e30f, M1=-1e30f, M2=-1e30f, M3=-1e30f;
  float S0=0.f, S1=0.f, S2=0.f, S3=0.f;

  for (int tile = w; tile < 17; tile += 4){
    const int colid = tile * 16 + nloc;
    const int jn = colid - 16;
    const bool isneg = colid >= 16;
    const int g = isneg ? (int)((aa * (unsigned)jn + bo) & 8191u) : (r0 + colid);

    const ushort* __restrict__ xr = x + ((size_t)g << 7);
    f4 acc = {0.f, 0.f, 0.f, 0.f};
    #pragma unroll
    for (int ks = 0; ks < 4; ks++){
      const bf8 bfr = *(const bf8*)(xr + ks * 32 + kg * 8);
      acc = __builtin_amdgcn_mfma_f32_16x16x32_bf16(af[ks], bfr, acc, 0, 0, 0);
    }
    #pragma unroll
    for (int r = 0; r < 4; r++){
      const int row = kg * 4 + r;
      const bool valid = isneg ? (jn < 255 && g != r0 + row) : (colid == row);
      const float v = acc[r] * 10.0f;
      if (!isneg && colid == row) lpos[row] = v;   // only tile 0 (wave 0)
      float* Mp; float* Sp;
      if (r == 0){ Mp = &M0; Sp = &S0; } else if (r == 1){ Mp = &M1; Sp = &S1; }
      else if (r == 2){ Mp = &M2; Sp = &S2; } else { Mp = &M3; Sp = &S3; }
      if (valid){
        const float Mn = fmaxf(*Mp, v);
        *Sp = *Sp * __expf(*Mp - Mn) + __expf(v - Mn);
        *Mp = Mn;
      }
    }
  }

  #define MERGE_LANES(MV, SV)                          \
  {                                                    \
    _Pragma("unroll")                                  \
    for (int o = 1; o < 16; o <<= 1){                  \
      const float Mo = __shfl_xor((MV), o);            \
      const float So = __shfl_xor((SV), o);            \
      const float Mn = fmaxf((MV), Mo);                \
      (SV) = (SV) * __expf((MV) - Mn) + So * __expf(Mo - Mn); \
      (MV) = Mn;                                       \
    }                                                  \
  }
  MERGE_LANES(M0, S0) MERGE_LANES(M1, S1) MERGE_LANES(M2, S2) MERGE_LANES(M3, S3)
  #undef MERGE_LANES

  if (nloc == 0){
    part[w][kg * 4 + 0] = make_float2(M0, S0);
    part[w][kg * 4 + 1] = make_float2(M1, S1);
    part[w][kg * 4 + 2] = make_float2(M2, S2);
    part[w][kg * 4 + 3] = make_float2(M3, S3);
  }
  __syncthreads();

  if (w == 0 && l < 16){
    const int row = l;
    float Mm = -1e30f, Ss = 0.f;
    #pragma unroll
    for (int j = 0; j < 4; j++){
      const float2 ps = part[j][row];
      const float Mn = fmaxf(Mm, ps.x);
      Ss = Ss * __expf(Mm - Mn) + ps.y * __expf(ps.x - Mn);
      Mm = Mn;
    }
    float term = Mm + __logf(Ss) - lpos[row];
    #pragma unroll
    for (int o = 8; o >= 1; o >>= 1) term += __shfl_xor(term, o);
    if (l == 0) atomicAdd(out, term / (logf(256.0f) * (float)(2 * n)));
  }
}

extern "C" void kernel_launch(void* const* d_in, const int* in_sizes, int n_in,
                              void* d_out, int out_size, void* d_ws, size_t ws_size,
                              hipStream_t stream) {
  const float* x_a = (const float*)d_in[0];
  const float* x_b = (const float*)d_in[1];
  const float* W_a = (const float*)d_in[2];
  const float* b_a = (const float*)d_in[3];
  const float* W_b = (const float*)d_in[4];
  const float* b_b = (const float*)d_in[5];
  const int*   e_ab = (const int*)d_in[6];   // [2,E]: [0]=src(a), [1]=dst(b)
  const int*   e_ba = (const int*)d_in[7];   // [0]=src(b), [1]=dst(a)
  const int E = in_sizes[6] / 2;
  const int N = in_sizes[0] / D;             // 8192

  char* p = (char*)d_ws;
  ushort* xa16   = (ushort*)p; p += (size_t)N * D * 2;
  ushort* xb16   = (ushort*)p; p += (size_t)N * D * 2;
  ushort* ctx0a  = (ushort*)p; p += (size_t)N * D * 2;
  ushort* ctx0b  = (ushort*)p; p += (size_t)N * D * 2;
  int*    cnt    = (int*)p;    p += (size_t)2 * N * CPAD * 4;   // 1MB padded
  int*    csr    = (int*)p;    p += (size_t)2 * N * DEG * 4;
  ushort* W16a   = (ushort*)p; p += (size_t)D * D * 2;
  ushort* W16b   = (ushort*)p; p += (size_t)D * D * 2;

  const int prep_threads = 2 * N * CPAD / 4;    // 65536 -> 256 blocks
  prep_kernel<<<(prep_threads + 255) / 256, 256, 0, stream>>>(
      W_a, W_b, W16a, W16b, cnt, (float*)d_out, N);

  linear_scatter<<<2 * (N / 64) + 2048, 256, 0, stream>>>(
      x_a, x_b, W16a, W16b, b_a, b_b, xa16, xb16, ctx0a, ctx0b,
      e_ba, e_ab, cnt, csr, E, N);

  loss_fused<<<2 * (N / 16), 256, 0, stream>>>(
      xa16, xb16, ctx0a, ctx0b, cnt, csr, (float*)d_out, N);
}

// Round 4
// 67.101 us; speedup vs baseline: 1.1012x; 1.1012x over previous
//
#include <hip/hip_runtime.h>
#include <math.h>

#define D 128
#define DEG 64           // CSR slot capacity per node (mean degree 32, P(any overflow)~2e-5)

typedef __attribute__((ext_vector_type(8))) short bf8;
typedef __attribute__((ext_vector_type(4))) float f4;

__device__ __forceinline__ unsigned hash_u32(unsigned x){
  x ^= x >> 16; x *= 0x7feb352du; x ^= x >> 15; x *= 0x846ca68bu; x ^= x >> 16;
  return x;
}
__device__ __forceinline__ unsigned f2bfbits(float f){
  unsigned u = __float_as_uint(f);
  return (u + 0x7fffu + ((u >> 16) & 1u)) >> 16;   // RNE bf16
}
__device__ __forceinline__ float bflo(unsigned u){ return __uint_as_float(u << 16); }
__device__ __forceinline__ float bfhi(unsigned u){ return __uint_as_float(u & 0xffff0000u); }
__device__ __forceinline__ uint4 pack8(float4 v0, float4 v1){
  uint4 o;
  o.x = f2bfbits(v0.x) | (f2bfbits(v0.y) << 16);
  o.y = f2bfbits(v0.z) | (f2bfbits(v0.w) << 16);
  o.z = f2bfbits(v1.x) | (f2bfbits(v1.y) << 16);
  o.w = f2bfbits(v1.z) | (f2bfbits(v1.w) << 16);
  return o;
}

// XCD-aware type partition (perf heuristic; bijective, correctness-neutral).
__device__ __forceinline__ int xcd_remap(int bid, int jobs_per_type){
  if (jobs_per_type & 3) return bid;               // fallback: identity
  const int xcd = bid & 7, slot = bid >> 3;
  const int q = jobs_per_type >> 2;                // jobs per XCD within a type
  return (xcd >> 2) * jobs_per_type + (xcd & 3) * q + slot;
}

// ---- K1: zero cnt (64KB) + out, convert W once (64KB) ---------------------
__global__ __launch_bounds__(256)
void prep_kernel(const float* __restrict__ Wa, const float* __restrict__ Wb,
                 ushort* __restrict__ W16a, ushort* __restrict__ W16b,
                 int* __restrict__ cnt, float* __restrict__ out0, int N){
  const int tid = blockIdx.x * 256 + threadIdx.x;
  const int ncnt4 = (2 * N) / 4;                  // 4096 uint4 = 64KB
  if (tid < ncnt4) ((uint4*)cnt)[tid] = uint4{0u, 0u, 0u, 0u};
  if (tid < 2 * (D * D / 8)){                     // 4096 threads convert both W
    const int ty = tid >= D * D / 8;
    const int k = tid - (ty ? D * D / 8 : 0);
    const float* __restrict__ src = ty ? Wb : Wa;
    ushort* __restrict__ dst = ty ? W16b : W16a;
    const float4 v0 = *(const float4*)(src + k * 8);
    const float4 v1 = *(const float4*)(src + k * 8 + 4);
    *(uint4*)(dst + k * 8) = pack8(v0, v1);
  }
  if (tid == 0) *out0 = 0.0f;
}

// ---- K2: linear (fp32 x -> LDS bf16 tiles -> MFMA, emits x16) + scatter ---
// Scatter is dst-range partitioned: per direction, 4 groups each own a dst
// quarter; a group's 256 blocks stripe-scan the WHOLE edge list and keep only
// their quarter. Every csr/cnt line is then written from ONE XCD -> stores
// merge in that L2 -> writebacks ~6MB instead of 64B/edge = 33.7MB (round-3
// counter evidence). Scan amplification x4 on edge reads is L2/LLC-cheap.
__global__ __launch_bounds__(256)
void linear_scatter(const float* __restrict__ xa, const float* __restrict__ xb,
                    const ushort* __restrict__ W16a, const ushort* __restrict__ W16b,
                    const float* __restrict__ ba, const float* __restrict__ bb,
                    ushort* __restrict__ x16a, ushort* __restrict__ x16b,
                    ushort* __restrict__ oa, ushort* __restrict__ ob,
                    const int* __restrict__ e_ba, const int* __restrict__ e_ab,
                    int* __restrict__ cnt, int* __restrict__ csr,
                    int E, int N){
  const int LB = 2 * (N >> 6);                   // 256 linear blocks (LB%8==0)
  __shared__ alignas(16) ushort As[4][16 * 128]; // 16KB, linear branch only

  if ((int)blockIdx.x < LB){
    // ---------------- ctx0 = bf16(x @ W^T + b) via MFMA ----------------
    const int nb64 = N >> 6;
    const int jid = xcd_remap((int)blockIdx.x, nb64);
    const int type = jid >= nb64;
    const int r0 = (jid - (type ? nb64 : 0)) << 6;
    const float* __restrict__ x = type ? xb : xa;
    const ushort* __restrict__ W16 = type ? W16b : W16a;
    const float* __restrict__ bias = type ? bb : ba;
    ushort* __restrict__ x16 = type ? x16b : x16a;
    ushort* __restrict__ out = type ? ob : oa;
    const int t = threadIdx.x, w = t >> 6, l = t & 63;

    // stage this wave's 16 rows: fp32 -> bf16 into LDS + coalesced x16 emit
    #pragma unroll
    for (int i = 0; i < 4; i++){
      const int cid = i * 64 + l;
      const int row = cid >> 4, kq = cid & 15;
      const size_t gr = (size_t)(r0 + w * 16 + row);
      const float4 v0 = *(const float4*)(x + (gr << 7) + (kq << 3));
      const float4 v1 = *(const float4*)(x + (gr << 7) + (kq << 3) + 4);
      const uint4 o = pack8(v0, v1);
      *(uint4*)&As[w][(row << 7) + ((kq ^ (row & 7)) << 3)] = o;
      *(uint4*)(x16 + (gr << 7) + (kq << 3)) = o;  // 1KB/instr coalesced
    }
    __syncthreads();

    const int rloc = l & 15, kg = l >> 4;
    bf8 af[4];
    #pragma unroll
    for (int ks = 0; ks < 4; ks++){
      const int kq = ks * 4 + kg;
      af[ks] = *(const bf8*)&As[w][(rloc << 7) + ((kq ^ (rloc & 7)) << 3)];
    }
    #pragma unroll
    for (int ct = 0; ct < 8; ct++){
      const int col = ct * 16 + rloc;
      const ushort* __restrict__ wr = W16 + ((size_t)col << 7);  // L2/L1-hot 32KB
      f4 acc = {0.f, 0.f, 0.f, 0.f};
      #pragma unroll
      for (int ks = 0; ks < 4; ks++){
        const bf8 bfr = *(const bf8*)(wr + ks * 32 + kg * 8);
        acc = __builtin_amdgcn_mfma_f32_16x16x32_bf16(af[ks], bfr, acc, 0, 0, 0);
      }
      const float bv = bias[col];
      #pragma unroll
      for (int r = 0; r < 4; r++){
        const int row = r0 + w * 16 + kg * 4 + r;
        out[((size_t)row << 7) + col] = (ushort)f2bfbits(acc[r] + bv);
      }
    }
  } else {
    // ------------- dst-range-partitioned CSR scatter -------------------
    const int bid2 = (int)blockIdx.x - LB;       // 0..2047; blockIdx%8 parity kept
    const int xcd = bid2 & 7;                    // heuristic XCD id
    const bool sb = (xcd & 4) != 0;              // XCDs 0-3: dir ba, 4-7: dir ab
    const int grp = xcd & 3;                     // dst quarter within direction
    const int stripe = bid2 >> 3;                // 0..255
    const int* __restrict__ e = sb ? e_ab : e_ba;
    const int base = sb ? N : 0;
    const int qN = N >> 2;
    const int dlo = grp * qN, dhi = dlo + qN;
    // stripes x threads x 4 edges cover E exactly when E = 256*256*4; the
    // grid-stride loop generalizes. (E assumed %4==0; E=262144 here.)
    for (int i = (stripe * 256 + (int)threadIdx.x) * 4; i < E; i += 256 * 256 * 4){
      const int4 d4 = *(const int4*)(e + E + i);   // 4 dsts, coalesced
      const int4 s4 = *(const int4*)(e + i);       // 4 srcs, coalesced
      #pragma unroll
      for (int k = 0; k < 4; k++){
        const int dst = (k == 0) ? d4.x : (k == 1) ? d4.y : (k == 2) ? d4.z : d4.w;
        if (dst >= dlo && dst < dhi){
          const int src = (k == 0) ? s4.x : (k == 1) ? s4.y : (k == 2) ? s4.z : s4.w;
          const int node = base + dst;
          const int p = atomicAdd(&cnt[node], 1);
          if (p < DEG) csr[(size_t)node * DEG + p] = src;
        }
      }
    }
  }
}

// ---- K3: fused gather-mean + contrastive loss -----------------------------
__global__ __launch_bounds__(256)
void loss_fused(const ushort* __restrict__ xa, const ushort* __restrict__ xb,
                const ushort* __restrict__ ctx0a, const ushort* __restrict__ ctx0b,
                const int* __restrict__ cnt, const int* __restrict__ csr,
                float* __restrict__ out, int n){
  const int nb = n >> 4;                          // 512 jobs per type
  const int jid = xcd_remap((int)blockIdx.x, nb); // XCDs 0-3: type 0, XCDs 4-7: type 1
  const int type = jid >= nb;
  const int r0 = (jid - (type ? nb : 0)) << 4;
  const ushort* __restrict__ x    = type ? xb : xa;
  const ushort* __restrict__ feat = type ? ctx0a : ctx0b;  // src-side features
  const int nodebase = type ? n : 0;
  const int t = threadIdx.x, w = t >> 6, l = t & 63;
  const int sg = l >> 4, q = l & 15;

  __shared__ alignas(16) ushort A[16 * 128];      // 4KB ctx rows, swizzled
  __shared__ float lpos[16];
  __shared__ float2 part[4][16];

  const unsigned h = hash_u32((unsigned)jid * 2654435761u + 0x9E3779B9u);
  const unsigned bo = h & 8191u;
  const unsigned aa = (((h >> 13) & 4095u) << 1) | 1u;   // odd -> distinct mod 8192

  { // ---- phase 1: gather-mean for node row = w*4+sg (static-unrolled) ----
    const int row = w * 4 + sg;
    const int node = nodebase + r0 + row;
    const int c = min(cnt[node], DEG);
    const size_t sbase = (size_t)node * DEG;
    int sl0 = csr[sbase + q];
    int sl1 = csr[sbase + 16 + q];
    int sl2 = csr[sbase + 32 + q];
    int sl3 = csr[sbase + 48 + q];

    float a0=0.f,a1=0.f,a2=0.f,a3=0.f,a4=0.f,a5=0.f,a6=0.f,a7=0.f;
    const int lbase = l & 48;
    #define GMEAN_CHUNK(SL, J)                                                 \
    if (c > (J)*16){                                                           \
      _Pragma("unroll")                                                        \
      for (int i = 0; i < 16; i++){                                            \
        const int raw = __shfl((SL), lbase | i, 64);                           \
        const bool ok = (J)*16 + i < c;                                        \
        const int src = ok ? raw : 0;                                          \
        const float wt = ok ? 1.0f : 0.0f;                                     \
        const uint4 v = *(const uint4*)(feat + ((size_t)src << 7) + (q << 3)); \
        a0 += wt*bflo(v.x); a1 += wt*bfhi(v.x); a2 += wt*bflo(v.y); a3 += wt*bfhi(v.y); \
        a4 += wt*bflo(v.z); a5 += wt*bfhi(v.z); a6 += wt*bflo(v.w); a7 += wt*bfhi(v.w); \
      }                                                                        \
    }
    GMEAN_CHUNK(sl0, 0) GMEAN_CHUNK(sl1, 1) GMEAN_CHUNK(sl2, 2) GMEAN_CHUNK(sl3, 3)
    #undef GMEAN_CHUNK

    const float inv = 1.0f / (float)(c > 1 ? c : 1);
    uint4 o;
    o.x = f2bfbits(a0*inv) | (f2bfbits(a1*inv) << 16);
    o.y = f2bfbits(a2*inv) | (f2bfbits(a3*inv) << 16);
    o.z = f2bfbits(a4*inv) | (f2bfbits(a5*inv) << 16);
    o.w = f2bfbits(a6*inv) | (f2bfbits(a7*inv) << 16);
    *(uint4*)&A[(row << 7) + ((q ^ (row & 7)) << 3)] = o;
  }
  __syncthreads();

  // ---- phase 2: MFMA tiles with direct-global B, online LSE ----
  const int nloc = l & 15, kg = l >> 4;
  bf8 af[4];
  #pragma unroll
  for (int ks = 0; ks < 4; ks++){
    const int kq = ks * 4 + kg;
    af[ks] = *(const bf8*)&A[(nloc << 7) + ((kq ^ (nloc & 7)) << 3)];
  }

  float M0=-1e30f, M1=-1e30f, M2=-1e30f, M3=-1e30f;
  float S0=0.f, S1=0.f, S2=0.f, S3=0.f;

  for (int tile = w; tile < 17; tile += 4){
    const int colid = tile * 16 + nloc;
    const int jn = colid - 16;
    const bool isneg = colid >= 16;
    const int g = isneg ? (int)((aa * (unsigned)jn + bo) & 8191u) : (r0 + colid);

    const ushort* __restrict__ xr = x + ((size_t)g << 7);
    f4 acc = {0.f, 0.f, 0.f, 0.f};
    #pragma unroll
    for (int ks = 0; ks < 4; ks++){
      const bf8 bfr = *(const bf8*)(xr + ks * 32 + kg * 8);
      acc = __builtin_amdgcn_mfma_f32_16x16x32_bf16(af[ks], bfr, acc, 0, 0, 0);
    }
    #pragma unroll
    for (int r = 0; r < 4; r++){
      const int row = kg * 4 + r;
      const bool valid = isneg ? (jn < 255 && g != r0 + row) : (colid == row);
      const float v = acc[r] * 10.0f;
      if (!isneg && colid == row) lpos[row] = v;   // only tile 0 (wave 0)
      float* Mp; float* Sp;
      if (r == 0){ Mp = &M0; Sp = &S0; } else if (r == 1){ Mp = &M1; Sp = &S1; }
      else if (r == 2){ Mp = &M2; Sp = &S2; } else { Mp = &M3; Sp = &S3; }
      if (valid){
        const float Mn = fmaxf(*Mp, v);
        *Sp = *Sp * __expf(*Mp - Mn) + __expf(v - Mn);
        *Mp = Mn;
      }
    }
  }

  #define MERGE_LANES(MV, SV)                          \
  {                                                    \
    _Pragma("unroll")                                  \
    for (int o = 1; o < 16; o <<= 1){                  \
      const float Mo = __shfl_xor((MV), o);            \
      const float So = __shfl_xor((SV), o);            \
      const float Mn = fmaxf((MV), Mo);                \
      (SV) = (SV) * __expf((MV) - Mn) + So * __expf(Mo - Mn); \
      (MV) = Mn;                                       \
    }                                                  \
  }
  MERGE_LANES(M0, S0) MERGE_LANES(M1, S1) MERGE_LANES(M2, S2) MERGE_LANES(M3, S3)
  #undef MERGE_LANES

  if (nloc == 0){
    part[w][kg * 4 + 0] = make_float2(M0, S0);
    part[w][kg * 4 + 1] = make_float2(M1, S1);
    part[w][kg * 4 + 2] = make_float2(M2, S2);
    part[w][kg * 4 + 3] = make_float2(M3, S3);
  }
  __syncthreads();

  if (w == 0 && l < 16){
    const int row = l;
    float Mm = -1e30f, Ss = 0.f;
    #pragma unroll
    for (int j = 0; j < 4; j++){
      const float2 ps = part[j][row];
      const float Mn = fmaxf(Mm, ps.x);
      Ss = Ss * __expf(Mm - Mn) + ps.y * __expf(ps.x - Mn);
      Mm = Mn;
    }
    float term = Mm + __logf(Ss) - lpos[row];
    #pragma unroll
    for (int o = 8; o >= 1; o >>= 1) term += __shfl_xor(term, o);
    if (l == 0) atomicAdd(out, term / (logf(256.0f) * (float)(2 * n)));
  }
}

extern "C" void kernel_launch(void* const* d_in, const int* in_sizes, int n_in,
                              void* d_out, int out_size, void* d_ws, size_t ws_size,
                              hipStream_t stream) {
  const float* x_a = (const float*)d_in[0];
  const float* x_b = (const float*)d_in[1];
  const float* W_a = (const float*)d_in[2];
  const float* b_a = (const float*)d_in[3];
  const float* W_b = (const float*)d_in[4];
  const float* b_b = (const float*)d_in[5];
  const int*   e_ab = (const int*)d_in[6];   // [2,E]: [0]=src(a), [1]=dst(b)
  const int*   e_ba = (const int*)d_in[7];   // [0]=src(b), [1]=dst(a)
  const int E = in_sizes[6] / 2;
  const int N = in_sizes[0] / D;             // 8192

  char* p = (char*)d_ws;
  ushort* xa16   = (ushort*)p; p += (size_t)N * D * 2;
  ushort* xb16   = (ushort*)p; p += (size_t)N * D * 2;
  ushort* ctx0a  = (ushort*)p; p += (size_t)N * D * 2;
  ushort* ctx0b  = (ushort*)p; p += (size_t)N * D * 2;
  int*    cnt    = (int*)p;    p += (size_t)2 * N * 4;
  int*    csr    = (int*)p;    p += (size_t)2 * N * DEG * 4;
  ushort* W16a   = (ushort*)p; p += (size_t)D * D * 2;
  ushort* W16b   = (ushort*)p; p += (size_t)D * D * 2;

  prep_kernel<<<16, 256, 0, stream>>>(
      W_a, W_b, W16a, W16b, cnt, (float*)d_out, N);

  linear_scatter<<<2 * (N / 64) + 2048, 256, 0, stream>>>(
      x_a, x_b, W16a, W16b, b_a, b_b, xa16, xb16, ctx0a, ctx0b,
      e_ba, e_ab, cnt, csr, E, N);

  loss_fused<<<2 * (N / 16), 256, 0, stream>>>(
      xa16, xb16, ctx0a, ctx0b, cnt, csr, (float*)d_out, N);
}

// Round 5
// 60.037 us; speedup vs baseline: 1.2308x; 1.1177x over previous
//
#include <hip/hip_runtime.h>
#include <math.h>

#define D 128
#define DEG 64           // CSR slot capacity per node (mean degree 32, P(any overflow)~2e-5)
#define BK 128           // dst buckets per direction (64 nodes/bucket)
#define SCAP 2560        // scratch capacity per bucket (mean 2048, +10 sigma)

typedef __attribute__((ext_vector_type(8))) short bf8;
typedef __attribute__((ext_vector_type(4))) float f4;

__device__ __forceinline__ unsigned hash_u32(unsigned x){
  x ^= x >> 16; x *= 0x7feb352du; x ^= x >> 15; x *= 0x846ca68bu; x ^= x >> 16;
  return x;
}
__device__ __forceinline__ unsigned f2bfbits(float f){
  unsigned u = __float_as_uint(f);
  return (u + 0x7fffu + ((u >> 16) & 1u)) >> 16;   // RNE bf16
}
__device__ __forceinline__ float bflo(unsigned u){ return __uint_as_float(u << 16); }
__device__ __forceinline__ float bfhi(unsigned u){ return __uint_as_float(u & 0xffff0000u); }
__device__ __forceinline__ uint4 pack8(float4 v0, float4 v1){
  uint4 o;
  o.x = f2bfbits(v0.x) | (f2bfbits(v0.y) << 16);
  o.y = f2bfbits(v0.z) | (f2bfbits(v0.w) << 16);
  o.z = f2bfbits(v1.x) | (f2bfbits(v1.y) << 16);
  o.w = f2bfbits(v1.z) | (f2bfbits(v1.w) << 16);
  return o;
}

// XCD-aware type partition (perf heuristic; bijective, correctness-neutral).
__device__ __forceinline__ int xcd_remap(int bid, int jobs_per_type){
  if (jobs_per_type & 3) return bid;               // fallback: identity
  const int xcd = bid & 7, slot = bid >> 3;
  const int q = jobs_per_type >> 2;                // jobs per XCD within a type
  return (xcd >> 2) * jobs_per_type + (xcd & 3) * q + slot;
}

// ---- K1: zero gcnt + out, convert W once (64KB) ---------------------------
__global__ __launch_bounds__(256)
void prep_kernel(const float* __restrict__ Wa, const float* __restrict__ Wb,
                 ushort* __restrict__ W16a, ushort* __restrict__ W16b,
                 int* __restrict__ gcnt, float* __restrict__ out0, int N){
  const int tid = blockIdx.x * 256 + threadIdx.x;
  if (tid < 2 * BK) gcnt[tid] = 0;
  if (tid < 2 * (D * D / 8)){                     // 4096 threads convert both W
    const int ty = tid >= D * D / 8;
    const int k = tid - (ty ? D * D / 8 : 0);
    const float* __restrict__ src = ty ? Wb : Wa;
    ushort* __restrict__ dst = ty ? W16b : W16a;
    const float4 v0 = *(const float4*)(src + k * 8);
    const float4 v1 = *(const float4*)(src + k * 8 + 4);
    *(uint4*)(dst + k * 8) = pack8(v0, v1);
  }
  if (tid == 0) *out0 = 0.0f;
}

// ---- K2: linear (fp32 x -> LDS bf16 tiles -> MFMA, emits x16) + S1 binning
// S1 replaces the direct scatter: round-3 counters showed WRITE_SIZE = 64B x
// #edges (every 4B csr store = one partial-line HBM RMW transaction ~ 35us).
// S1 LDS-bins 1024 edges/block into 128 dst-buckets/direction, reserves global
// bucket space with ONE aggregated atomic per (block,bucket) (65K vs 524K),
// and writes packed (src|dst<<13) u32s in bucket-contiguous runs (~8-16x fewer
// write transactions). Scratch is 2.6MB (cache-resident, dead after csr_build).
__global__ __launch_bounds__(256)
void linear_scatter(const float* __restrict__ xa, const float* __restrict__ xb,
                    const ushort* __restrict__ W16a, const ushort* __restrict__ W16b,
                    const float* __restrict__ ba, const float* __restrict__ bb,
                    ushort* __restrict__ x16a, ushort* __restrict__ x16b,
                    ushort* __restrict__ oa, ushort* __restrict__ ob,
                    const int* __restrict__ e_ba, const int* __restrict__ e_ab,
                    int* __restrict__ gcnt, unsigned* __restrict__ scratch,
                    int E, int N){
  const int LB = 2 * (N >> 6);                   // 256 linear blocks (LB%8==0)
  __shared__ alignas(16) ushort As[4][16 * 128]; // 16KB, linear branch only

  if ((int)blockIdx.x < LB){
    // ---------------- ctx0 = bf16(x @ W^T + b) via MFMA ----------------
    const int nb64 = N >> 6;
    const int jid = xcd_remap((int)blockIdx.x, nb64);
    const int type = jid >= nb64;
    const int r0 = (jid - (type ? nb64 : 0)) << 6;
    const float* __restrict__ x = type ? xb : xa;
    const ushort* __restrict__ W16 = type ? W16b : W16a;
    const float* __restrict__ bias = type ? bb : ba;
    ushort* __restrict__ x16 = type ? x16b : x16a;
    ushort* __restrict__ out = type ? ob : oa;
    const int t = threadIdx.x, w = t >> 6, l = t & 63;

    #pragma unroll
    for (int i = 0; i < 4; i++){
      const int cid = i * 64 + l;
      const int row = cid >> 4, kq = cid & 15;
      const size_t gr = (size_t)(r0 + w * 16 + row);
      const float4 v0 = *(const float4*)(x + (gr << 7) + (kq << 3));
      const float4 v1 = *(const float4*)(x + (gr << 7) + (kq << 3) + 4);
      const uint4 o = pack8(v0, v1);
      *(uint4*)&As[w][(row << 7) + ((kq ^ (row & 7)) << 3)] = o;
      *(uint4*)(x16 + (gr << 7) + (kq << 3)) = o;  // 1KB/instr coalesced
    }
    __syncthreads();

    const int rloc = l & 15, kg = l >> 4;
    bf8 af[4];
    #pragma unroll
    for (int ks = 0; ks < 4; ks++){
      const int kq = ks * 4 + kg;
      af[ks] = *(const bf8*)&As[w][(rloc << 7) + ((kq ^ (rloc & 7)) << 3)];
    }
    #pragma unroll
    for (int ct = 0; ct < 8; ct++){
      const int col = ct * 16 + rloc;
      const ushort* __restrict__ wr = W16 + ((size_t)col << 7);  // L2/L1-hot 32KB
      f4 acc = {0.f, 0.f, 0.f, 0.f};
      #pragma unroll
      for (int ks = 0; ks < 4; ks++){
        const bf8 bfr = *(const bf8*)(wr + ks * 32 + kg * 8);
        acc = __builtin_amdgcn_mfma_f32_16x16x32_bf16(af[ks], bfr, acc, 0, 0, 0);
      }
      const float bv = bias[col];
      #pragma unroll
      for (int r = 0; r < 4; r++){
        const int row = r0 + w * 16 + kg * 4 + r;
        out[((size_t)row << 7) + col] = (ushort)f2bfbits(acc[r] + bv);
      }
    }
  } else {
    // ---------------- S1: LDS-binned edge bucketing --------------------
    const int sbid = (int)blockIdx.x - LB;       // 0..511
    const int d = sbid >> 8;                     // direction: 0=ba, 1=ab
    const int chunk = sbid & 255;
    const int* __restrict__ e = d ? e_ab : e_ba;
    const int t = threadIdx.x;
    __shared__ int hist[BK], gb[BK], ex[BK], cur[BK];
    __shared__ unsigned buf[1024];
    if (t < BK) hist[t] = 0;
    __syncthreads();

    int ds[4], ss[4];
    const int base = chunk * 1024;
    #pragma unroll
    for (int k = 0; k < 4; k++){
      const int i = base + k * 256 + t;
      const bool ok = i < E;
      ds[k] = ok ? e[E + i] : -1;
      ss[k] = ok ? e[i] : 0;
      if (ok) atomicAdd(&hist[ds[k] >> 6], 1);   // LDS atomic
    }
    __syncthreads();
    if (t < BK) gb[t] = atomicAdd(&gcnt[d * BK + t], hist[t]);  // 1 global atomic/bucket
    if (t < BK) ex[t] = hist[t];
    __syncthreads();
    // Hillis-Steele inclusive scan over 128 bins
    for (int off = 1; off < BK; off <<= 1){
      int v = 0;
      if (t < BK && t >= off) v = ex[t - off];
      __syncthreads();
      if (t < BK) ex[t] += v;
      __syncthreads();
    }
    if (t < BK){ ex[t] -= hist[t]; cur[t] = ex[t]; }  // exclusive starts
    __syncthreads();
    int nv = E - base; nv = nv < 0 ? 0 : (nv > 1024 ? 1024 : nv);
    #pragma unroll
    for (int k = 0; k < 4; k++){
      if (ds[k] >= 0){
        const int p = atomicAdd(&cur[ds[k] >> 6], 1);            // LDS atomic
        buf[p] = (unsigned)ss[k] | ((unsigned)ds[k] << 13);
      }
    }
    __syncthreads();
    // write out bucket-contiguous runs
    for (int s = t; s < nv; s += 256){
      const unsigned v = buf[s];
      const int bkt = (int)(v >> 19);            // dst>>6
      const int gp = gb[bkt] + (s - ex[bkt]);
      if (gp < SCAP) scratch[(size_t)(d * BK + bkt) * SCAP + gp] = v;
    }
  }
}

// ---- K2b: per-bucket CSR build, fully coalesced writes --------------------
__global__ __launch_bounds__(256)
void csr_build(const unsigned* __restrict__ scratch, const int* __restrict__ gcnt,
               int* __restrict__ cnt, int* __restrict__ csr, int N){
  const int bid = (int)blockIdx.x;               // 0..255
  const int d = bid >> 7, bkt = bid & 127;
  const int t = threadIdx.x;
  __shared__ int slots[64 * DEG];                // 16KB
  __shared__ int lcnt[64];
  if (t < 64) lcnt[t] = 0;
  __syncthreads();
  const int size = min(gcnt[d * BK + bkt], SCAP);
  const unsigned* __restrict__ src = scratch + (size_t)(d * BK + bkt) * SCAP;
  for (int i = t; i < size; i += 256){
    const unsigned v = src[i];                   // contiguous, coalesced
    const int node = (int)((v >> 13) & 63u);
    const int p = atomicAdd(&lcnt[node], 1);     // LDS atomic
    if (p < DEG) slots[node * DEG + p] = (int)(v & 8191u);
  }
  __syncthreads();
  const int nodebase = d * N + bkt * 64;
  if (t < 64) cnt[nodebase + t] = lcnt[t];       // true degree (K3 caps at DEG)
  const size_t cbase = (size_t)nodebase * DEG;
  for (int j = t; j < 64 * DEG; j += 256)
    csr[cbase + j] = slots[j];                   // 16KB contiguous, full lines
}

// ---- K3: fused gather-mean + contrastive loss -----------------------------
__global__ __launch_bounds__(256)
void loss_fused(const ushort* __restrict__ xa, const ushort* __restrict__ xb,
                const ushort* __restrict__ ctx0a, const ushort* __restrict__ ctx0b,
                const int* __restrict__ cnt, const int* __restrict__ csr,
                float* __restrict__ out, int n){
  const int nb = n >> 4;                          // 512 jobs per type
  const int jid = xcd_remap((int)blockIdx.x, nb); // XCDs 0-3: type 0, XCDs 4-7: type 1
  const int type = jid >= nb;
  const int r0 = (jid - (type ? nb : 0)) << 4;
  const ushort* __restrict__ x    = type ? xb : xa;
  const ushort* __restrict__ feat = type ? ctx0a : ctx0b;  // src-side features
  const int nodebase = type ? n : 0;
  const int t = threadIdx.x, w = t >> 6, l = t & 63;
  const int sg = l >> 4, q = l & 15;

  __shared__ alignas(16) ushort A[16 * 128];      // 4KB ctx rows, swizzled
  __shared__ float lpos[16];
  __shared__ float2 part[4][16];

  const unsigned h = hash_u32((unsigned)jid * 2654435761u + 0x9E3779B9u);
  const unsigned bo = h & 8191u;
  const unsigned aa = (((h >> 13) & 4095u) << 1) | 1u;   // odd -> distinct mod 8192

  { // ---- phase 1: gather-mean for node row = w*4+sg (static-unrolled) ----
    const int row = w * 4 + sg;
    const int node = nodebase + r0 + row;
    const int c = min(cnt[node], DEG);
    const size_t sbase = (size_t)node * DEG;
    int sl0 = csr[sbase + q];
    int sl1 = csr[sbase + 16 + q];
    int sl2 = csr[sbase + 32 + q];
    int sl3 = csr[sbase + 48 + q];

    float a0=0.f,a1=0.f,a2=0.f,a3=0.f,a4=0.f,a5=0.f,a6=0.f,a7=0.f;
    const int lbase = l & 48;
    #define GMEAN_CHUNK(SL, J)                                                 \
    if (c > (J)*16){                                                           \
      _Pragma("unroll")                                                        \
      for (int i = 0; i < 16; i++){                                            \
        const int raw = __shfl((SL), lbase | i, 64);                           \
        const bool ok = (J)*16 + i < c;                                        \
        const int src = ok ? raw : 0;                                          \
        const float wt = ok ? 1.0f : 0.0f;                                     \
        const uint4 v = *(const uint4*)(feat + ((size_t)src << 7) + (q << 3)); \
        a0 += wt*bflo(v.x); a1 += wt*bfhi(v.x); a2 += wt*bflo(v.y); a3 += wt*bfhi(v.y); \
        a4 += wt*bflo(v.z); a5 += wt*bfhi(v.z); a6 += wt*bflo(v.w); a7 += wt*bfhi(v.w); \
      }                                                                        \
    }
    GMEAN_CHUNK(sl0, 0) GMEAN_CHUNK(sl1, 1) GMEAN_CHUNK(sl2, 2) GMEAN_CHUNK(sl3, 3)
    #undef GMEAN_CHUNK

    const float inv = 1.0f / (float)(c > 1 ? c : 1);
    uint4 o;
    o.x = f2bfbits(a0*inv) | (f2bfbits(a1*inv) << 16);
    o.y = f2bfbits(a2*inv) | (f2bfbits(a3*inv) << 16);
    o.z = f2bfbits(a4*inv) | (f2bfbits(a5*inv) << 16);
    o.w = f2bfbits(a6*inv) | (f2bfbits(a7*inv) << 16);
    *(uint4*)&A[(row << 7) + ((q ^ (row & 7)) << 3)] = o;
  }
  __syncthreads();

  // ---- phase 2: MFMA tiles with direct-global B, online LSE ----
  const int nloc = l & 15, kg = l >> 4;
  bf8 af[4];
  #pragma unroll
  for (int ks = 0; ks < 4; ks++){
    const int kq = ks * 4 + kg;
    af[ks] = *(const bf8*)&A[(nloc << 7) + ((kq ^ (nloc & 7)) << 3)];
  }

  float M0=-1e30f, M1=-1e30f, M2=-1e30f, M3=-1e30f;
  float S0=0.f, S1=0.f, S2=0.f, S3=0.f;

  for (int tile = w; tile < 17; tile += 4){
    const int colid = tile * 16 + nloc;
    const int jn = colid - 16;
    const bool isneg = colid >= 16;
    const int g = isneg ? (int)((aa * (unsigned)jn + bo) & 8191u) : (r0 + colid);

    const ushort* __restrict__ xr = x + ((size_t)g << 7);
    f4 acc = {0.f, 0.f, 0.f, 0.f};
    #pragma unroll
    for (int ks = 0; ks < 4; ks++){
      const bf8 bfr = *(const bf8*)(xr + ks * 32 + kg * 8);
      acc = __builtin_amdgcn_mfma_f32_16x16x32_bf16(af[ks], bfr, acc, 0, 0, 0);
    }
    #pragma unroll
    for (int r = 0; r < 4; r++){
      const int row = kg * 4 + r;
      const bool valid = isneg ? (jn < 255 && g != r0 + row) : (colid == row);
      const float v = acc[r] * 10.0f;
      if (!isneg && colid == row) lpos[row] = v;   // only tile 0 (wave 0)
      float* Mp; float* Sp;
      if (r == 0){ Mp = &M0; Sp = &S0; } else if (r == 1){ Mp = &M1; Sp = &S1; }
      else if (r == 2){ Mp = &M2; Sp = &S2; } else { Mp = &M3; Sp = &S3; }
      if (valid){
        const float Mn = fmaxf(*Mp, v);
        *Sp = *Sp * __expf(*Mp - Mn) + __expf(v - Mn);
        *Mp = Mn;
      }
    }
  }

  #define MERGE_LANES(MV, SV)                          \
  {                                                    \
    _Pragma("unroll")                                  \
    for (int o = 1; o < 16; o <<= 1){                  \
      const float Mo = __shfl_xor((MV), o);            \
      const float So = __shfl_xor((SV), o);            \
      const float Mn = fmaxf((MV), Mo);                \
      (SV) = (SV) * __expf((MV) - Mn) + So * __expf(Mo - Mn); \
      (MV) = Mn;                                       \
    }                                                  \
  }
  MERGE_LANES(M0, S0) MERGE_LANES(M1, S1) MERGE_LANES(M2, S2) MERGE_LANES(M3, S3)
  #undef MERGE_LANES

  if (nloc == 0){
    part[w][kg * 4 + 0] = make_float2(M0, S0);
    part[w][kg * 4 + 1] = make_float2(M1, S1);
    part[w][kg * 4 + 2] = make_float2(M2, S2);
    part[w][kg * 4 + 3] = make_float2(M3, S3);
  }
  __syncthreads();

  if (w == 0 && l < 16){
    const int row = l;
    float Mm = -1e30f, Ss = 0.f;
    #pragma unroll
    for (int j = 0; j < 4; j++){
      const float2 ps = part[j][row];
      const float Mn = fmaxf(Mm, ps.x);
      Ss = Ss * __expf(Mm - Mn) + ps.y * __expf(ps.x - Mn);
      Mm = Mn;
    }
    float term = Mm + __logf(Ss) - lpos[row];
    #pragma unroll
    for (int o = 8; o >= 1; o >>= 1) term += __shfl_xor(term, o);
    if (l == 0) atomicAdd(out, term / (logf(256.0f) * (float)(2 * n)));
  }
}

extern "C" void kernel_launch(void* const* d_in, const int* in_sizes, int n_in,
                              void* d_out, int out_size, void* d_ws, size_t ws_size,
                              hipStream_t stream) {
  const float* x_a = (const float*)d_in[0];
  const float* x_b = (const float*)d_in[1];
  const float* W_a = (const float*)d_in[2];
  const float* b_a = (const float*)d_in[3];
  const float* W_b = (const float*)d_in[4];
  const float* b_b = (const float*)d_in[5];
  const int*   e_ab = (const int*)d_in[6];   // [2,E]: [0]=src(a), [1]=dst(b)
  const int*   e_ba = (const int*)d_in[7];   // [0]=src(b), [1]=dst(a)
  const int E = in_sizes[6] / 2;
  const int N = in_sizes[0] / D;             // 8192

  char* p = (char*)d_ws;
  ushort* xa16    = (ushort*)p;   p += (size_t)N * D * 2;
  ushort* xb16    = (ushort*)p;   p += (size_t)N * D * 2;
  ushort* ctx0a   = (ushort*)p;   p += (size_t)N * D * 2;
  ushort* ctx0b   = (ushort*)p;   p += (size_t)N * D * 2;
  int*    cnt     = (int*)p;      p += (size_t)2 * N * 4;
  int*    csr     = (int*)p;      p += (size_t)2 * N * DEG * 4;
  ushort* W16a    = (ushort*)p;   p += (size_t)D * D * 2;
  ushort* W16b    = (ushort*)p;   p += (size_t)D * D * 2;
  int*    gcnt    = (int*)p;      p += (size_t)2 * BK * 4;
  unsigned* scratch = (unsigned*)p; p += (size_t)2 * BK * SCAP * 4;

  prep_kernel<<<16, 256, 0, stream>>>(
      W_a, W_b, W16a, W16b, gcnt, (float*)d_out, N);

  linear_scatter<<<2 * (N / 64) + 512, 256, 0, stream>>>(
      x_a, x_b, W16a, W16b, b_a, b_b, xa16, xb16, ctx0a, ctx0b,
      e_ba, e_ab, gcnt, scratch, E, N);

  csr_build<<<2 * BK, 256, 0, stream>>>(scratch, gcnt, cnt, csr, N);

  loss_fused<<<2 * (N / 16), 256, 0, stream>>>(
      xa16, xb16, ctx0a, ctx0b, cnt, csr, (float*)d_out, N);
}

// Round 6
// 57.722 us; speedup vs baseline: 1.2801x; 1.0401x over previous
//
#include <hip/hip_runtime.h>
#include <math.h>

#define D 128
#define DEG 64           // per-node slot capacity (mean degree 32, P(any overflow)~0)
#define BK 128           // dst buckets per direction (64 nodes/bucket)
#define SCAP 2560        // scratch capacity per bucket (mean 2048, +11 sigma)

typedef __attribute__((ext_vector_type(8))) short bf8;
typedef __attribute__((ext_vector_type(4))) float f4;

__device__ __forceinline__ unsigned hash_u32(unsigned x){
  x ^= x >> 16; x *= 0x7feb352du; x ^= x >> 15; x *= 0x846ca68bu; x ^= x >> 16;
  return x;
}
__device__ __forceinline__ unsigned f2bfbits(float f){
  unsigned u = __float_as_uint(f);
  return (u + 0x7fffu + ((u >> 16) & 1u)) >> 16;   // RNE bf16
}
__device__ __forceinline__ float bflo(unsigned u){ return __uint_as_float(u << 16); }
__device__ __forceinline__ float bfhi(unsigned u){ return __uint_as_float(u & 0xffff0000u); }
__device__ __forceinline__ uint4 pack8(float4 v0, float4 v1){
  uint4 o;
  o.x = f2bfbits(v0.x) | (f2bfbits(v0.y) << 16);
  o.y = f2bfbits(v0.z) | (f2bfbits(v0.w) << 16);
  o.z = f2bfbits(v1.x) | (f2bfbits(v1.y) << 16);
  o.w = f2bfbits(v1.z) | (f2bfbits(v1.w) << 16);
  return o;
}

// XCD-aware type partition (perf heuristic; bijective, correctness-neutral).
__device__ __forceinline__ int xcd_remap(int bid, int jobs_per_type){
  if (jobs_per_type & 3) return bid;               // fallback: identity
  const int xcd = bid & 7, slot = bid >> 3;
  const int q = jobs_per_type >> 2;                // jobs per XCD within a type
  return (xcd >> 2) * jobs_per_type + (xcd & 3) * q + slot;
}

// ---- K1: zero gcnt + out, convert W once (64KB) ---------------------------
__global__ __launch_bounds__(256)
void prep_kernel(const float* __restrict__ Wa, const float* __restrict__ Wb,
                 ushort* __restrict__ W16a, ushort* __restrict__ W16b,
                 int* __restrict__ gcnt, float* __restrict__ out0, int N){
  const int tid = blockIdx.x * 256 + threadIdx.x;
  if (tid < 2 * BK) gcnt[tid] = 0;
  if (tid < 2 * (D * D / 8)){                     // 4096 threads convert both W
    const int ty = tid >= D * D / 8;
    const int k = tid - (ty ? D * D / 8 : 0);
    const float* __restrict__ src = ty ? Wb : Wa;
    ushort* __restrict__ dst = ty ? W16b : W16a;
    const float4 v0 = *(const float4*)(src + k * 8);
    const float4 v1 = *(const float4*)(src + k * 8 + 4);
    *(uint4*)(dst + k * 8) = pack8(v0, v1);
  }
  if (tid == 0) *out0 = 0.0f;
}

// ---- K2: linear (fp32 x -> LDS bf16 tiles -> MFMA, emits x16) + S1 binning
// S1: LDS-bins 1024 edges/block into 128 dst-buckets/direction, reserves
// global bucket space with ONE aggregated atomic per (block,bucket), writes
// packed (src|dst<<13) u32s in bucket-contiguous runs (coalesced). The CSR
// build kernel is GONE: loss blocks scan their bucket directly from scratch.
__global__ __launch_bounds__(256)
void linear_scatter(const float* __restrict__ xa, const float* __restrict__ xb,
                    const ushort* __restrict__ W16a, const ushort* __restrict__ W16b,
                    const float* __restrict__ ba, const float* __restrict__ bb,
                    ushort* __restrict__ x16a, ushort* __restrict__ x16b,
                    ushort* __restrict__ oa, ushort* __restrict__ ob,
                    const int* __restrict__ e_ba, const int* __restrict__ e_ab,
                    int* __restrict__ gcnt, unsigned* __restrict__ scratch,
                    int E, int N){
  const int LB = 2 * (N >> 6);                   // 256 linear blocks (LB%8==0)
  __shared__ alignas(16) ushort As[4][16 * 128]; // 16KB, linear branch only

  if ((int)blockIdx.x < LB){
    // ---------------- ctx0 = bf16(x @ W^T + b) via MFMA ----------------
    const int nb64 = N >> 6;
    const int jid = xcd_remap((int)blockIdx.x, nb64);
    const int type = jid >= nb64;
    const int r0 = (jid - (type ? nb64 : 0)) << 6;
    const float* __restrict__ x = type ? xb : xa;
    const ushort* __restrict__ W16 = type ? W16b : W16a;
    const float* __restrict__ bias = type ? bb : ba;
    ushort* __restrict__ x16 = type ? x16b : x16a;
    ushort* __restrict__ out = type ? ob : oa;
    const int t = threadIdx.x, w = t >> 6, l = t & 63;

    #pragma unroll
    for (int i = 0; i < 4; i++){
      const int cid = i * 64 + l;
      const int row = cid >> 4, kq = cid & 15;
      const size_t gr = (size_t)(r0 + w * 16 + row);
      const float4 v0 = *(const float4*)(x + (gr << 7) + (kq << 3));
      const float4 v1 = *(const float4*)(x + (gr << 7) + (kq << 3) + 4);
      const uint4 o = pack8(v0, v1);
      *(uint4*)&As[w][(row << 7) + ((kq ^ (row & 7)) << 3)] = o;
      *(uint4*)(x16 + (gr << 7) + (kq << 3)) = o;  // 1KB/instr coalesced
    }
    __syncthreads();

    const int rloc = l & 15, kg = l >> 4;
    bf8 af[4];
    #pragma unroll
    for (int ks = 0; ks < 4; ks++){
      const int kq = ks * 4 + kg;
      af[ks] = *(const bf8*)&As[w][(rloc << 7) + ((kq ^ (rloc & 7)) << 3)];
    }
    #pragma unroll
    for (int ct = 0; ct < 8; ct++){
      const int col = ct * 16 + rloc;
      const ushort* __restrict__ wr = W16 + ((size_t)col << 7);  // L2/L1-hot 32KB
      f4 acc = {0.f, 0.f, 0.f, 0.f};
      #pragma unroll
      for (int ks = 0; ks < 4; ks++){
        const bf8 bfr = *(const bf8*)(wr + ks * 32 + kg * 8);
        acc = __builtin_amdgcn_mfma_f32_16x16x32_bf16(af[ks], bfr, acc, 0, 0, 0);
      }
      const float bv = bias[col];
      #pragma unroll
      for (int r = 0; r < 4; r++){
        const int row = r0 + w * 16 + kg * 4 + r;
        out[((size_t)row << 7) + col] = (ushort)f2bfbits(acc[r] + bv);
      }
    }
  } else {
    // ---------------- S1: LDS-binned edge bucketing --------------------
    const int sbid = (int)blockIdx.x - LB;       // 0..511
    const int d = sbid >> 8;                     // direction: 0=ba, 1=ab
    const int chunk = sbid & 255;
    const int* __restrict__ e = d ? e_ab : e_ba;
    const int t = threadIdx.x;
    __shared__ int hist[BK], gb[BK], ex[BK], cur[BK];
    __shared__ unsigned buf[1024];
    if (t < BK) hist[t] = 0;
    __syncthreads();

    int ds[4], ss[4];
    const int base = chunk * 1024;
    #pragma unroll
    for (int k = 0; k < 4; k++){
      const int i = base + k * 256 + t;
      const bool ok = i < E;
      ds[k] = ok ? e[E + i] : -1;
      ss[k] = ok ? e[i] : 0;
      if (ok) atomicAdd(&hist[ds[k] >> 6], 1);   // LDS atomic
    }
    __syncthreads();
    if (t < BK) gb[t] = atomicAdd(&gcnt[d * BK + t], hist[t]);  // 1 global atomic/bucket
    if (t < BK) ex[t] = hist[t];
    __syncthreads();
    // Hillis-Steele inclusive scan over 128 bins
    for (int off = 1; off < BK; off <<= 1){
      int v = 0;
      if (t < BK && t >= off) v = ex[t - off];
      __syncthreads();
      if (t < BK) ex[t] += v;
      __syncthreads();
    }
    if (t < BK){ ex[t] -= hist[t]; cur[t] = ex[t]; }  // exclusive starts
    __syncthreads();
    int nv = E - base; nv = nv < 0 ? 0 : (nv > 1024 ? 1024 : nv);
    #pragma unroll
    for (int k = 0; k < 4; k++){
      if (ds[k] >= 0){
        const int p = atomicAdd(&cur[ds[k] >> 6], 1);            // LDS atomic
        buf[p] = (unsigned)ss[k] | ((unsigned)ds[k] << 13);
      }
    }
    __syncthreads();
    // write out bucket-contiguous runs
    for (int s = t; s < nv; s += 256){
      const unsigned v = buf[s];
      const int bkt = (int)(v >> 19);            // dst>>6
      const int gp = gb[bkt] + (s - ex[bkt]);
      if (gp < SCAP) scratch[(size_t)(d * BK + bkt) * SCAP + gp] = v;
    }
  }
}

// ---- K3: bucket-scan + gather-mean + contrastive loss (csr_build fused) ---
__global__ __launch_bounds__(256)
void loss_fused(const ushort* __restrict__ xa, const ushort* __restrict__ xb,
                const ushort* __restrict__ ctx0a, const ushort* __restrict__ ctx0b,
                const int* __restrict__ gcnt, const unsigned* __restrict__ scratch,
                float* __restrict__ out, int n){
  const int nb = n >> 4;                          // 512 jobs per type
  const int jid = xcd_remap((int)blockIdx.x, nb); // XCDs 0-3: type 0, XCDs 4-7: type 1
  const int type = jid >= nb;
  const int r0 = (jid - (type ? nb : 0)) << 4;
  const ushort* __restrict__ x    = type ? xb : xa;
  const ushort* __restrict__ feat = type ? ctx0a : ctx0b;  // src-side features
  const int t = threadIdx.x, w = t >> 6, l = t & 63;
  const int sg = l >> 4, q = l & 15;

  __shared__ alignas(16) ushort A[16 * 128];      // 4KB ctx rows, swizzled
  __shared__ float lpos[16];
  __shared__ float2 part[4][16];
  __shared__ int list[16 * DEG];                  // 4KB per-node src lists
  __shared__ int lcnt[16];

  const unsigned h = hash_u32((unsigned)jid * 2654435761u + 0x9E3779B9u);
  const unsigned bo = h & 8191u;
  const unsigned aa = (((h >> 13) & 4095u) << 1) | 1u;   // odd -> distinct mod 8192

  if (t < 16) lcnt[t] = 0;
  __syncthreads();

  { // ---- phase 0: scan this block's bucket (quarter ownership) ----------
    // type == direction index by construction (d=0: dst=a-nodes, d=1: b).
    const int bkt = r0 >> 6;
    const int seg = min(gcnt[type * BK + bkt], SCAP);
    const unsigned* __restrict__ sp = scratch + (size_t)(type * BK + bkt) * SCAP;
    for (int i = t; i < seg; i += 256){
      const unsigned v = sp[i];                   // contiguous, L2-hot
      const int dl = (int)((v >> 13) & 8191u) - r0;
      if ((unsigned)dl < 16u){
        const int p = atomicAdd(&lcnt[dl], 1);    // LDS atomic
        if (p < DEG) list[dl * DEG + p] = (int)(v & 8191u);
      }
    }
  }
  __syncthreads();

  { // ---- phase 1: gather-mean for node row = w*4+sg (lists in LDS) ------
    const int row = w * 4 + sg;
    const int c = min(lcnt[row], DEG);
    const int lb2 = row * DEG;
    int sl0 = list[lb2 + q];
    int sl1 = list[lb2 + 16 + q];
    int sl2 = list[lb2 + 32 + q];
    int sl3 = list[lb2 + 48 + q];

    float a0=0.f,a1=0.f,a2=0.f,a3=0.f,a4=0.f,a5=0.f,a6=0.f,a7=0.f;
    const int lbase = l & 48;
    #define GMEAN_CHUNK(SL, J)                                                 \
    if (c > (J)*16){                                                           \
      _Pragma("unroll")                                                        \
      for (int i = 0; i < 16; i++){                                            \
        const int raw = __shfl((SL), lbase | i, 64);                           \
        const bool ok = (J)*16 + i < c;                                        \
        const int src = ok ? raw : 0;                                          \
        const float wt = ok ? 1.0f : 0.0f;                                     \
        const uint4 v = *(const uint4*)(feat + ((size_t)src << 7) + (q << 3)); \
        a0 += wt*bflo(v.x); a1 += wt*bfhi(v.x); a2 += wt*bflo(v.y); a3 += wt*bfhi(v.y); \
        a4 += wt*bflo(v.z); a5 += wt*bfhi(v.z); a6 += wt*bflo(v.w); a7 += wt*bfhi(v.w); \
      }                                                                        \
    }
    GMEAN_CHUNK(sl0, 0) GMEAN_CHUNK(sl1, 1) GMEAN_CHUNK(sl2, 2) GMEAN_CHUNK(sl3, 3)
    #undef GMEAN_CHUNK

    const float inv = 1.0f / (float)(c > 1 ? c : 1);
    uint4 o;
    o.x = f2bfbits(a0*inv) | (f2bfbits(a1*inv) << 16);
    o.y = f2bfbits(a2*inv) | (f2bfbits(a3*inv) << 16);
    o.z = f2bfbits(a4*inv) | (f2bfbits(a5*inv) << 16);
    o.w = f2bfbits(a6*inv) | (f2bfbits(a7*inv) << 16);
    *(uint4*)&A[(row << 7) + ((q ^ (row & 7)) << 3)] = o;
  }
  __syncthreads();

  // ---- phase 2: MFMA tiles with direct-global B, online LSE ----
  const int nloc = l & 15, kg = l >> 4;
  bf8 af[4];
  #pragma unroll
  for (int ks = 0; ks < 4; ks++){
    const int kq = ks * 4 + kg;
    af[ks] = *(const bf8*)&A[(nloc << 7) + ((kq ^ (nloc & 7)) << 3)];
  }

  float M0=-1e30f, M1=-1e30f, M2=-1e30f, M3=-1e30f;
  float S0=0.f, S1=0.f, S2=0.f, S3=0.f;

  for (int tile = w; tile < 17; tile += 4){
    const int colid = tile * 16 + nloc;
    const int jn = colid - 16;
    const bool isneg = colid >= 16;
    const int g = isneg ? (int)((aa * (unsigned)jn + bo) & 8191u) : (r0 + colid);

    const ushort* __restrict__ xr = x + ((size_t)g << 7);
    f4 acc = {0.f, 0.f, 0.f, 0.f};
    #pragma unroll
    for (int ks = 0; ks < 4; ks++){
      const bf8 bfr = *(const bf8*)(xr + ks * 32 + kg * 8);
      acc = __builtin_amdgcn_mfma_f32_16x16x32_bf16(af[ks], bfr, acc, 0, 0, 0);
    }
    #pragma unroll
    for (int r = 0; r < 4; r++){
      const int row = kg * 4 + r;
      const bool valid = isneg ? (jn < 255 && g != r0 + row) : (colid == row);
      const float v = acc[r] * 10.0f;
      if (!isneg && colid == row) lpos[row] = v;   // only tile 0 (wave 0)
      float* Mp; float* Sp;
      if (r == 0){ Mp = &M0; Sp = &S0; } else if (r == 1){ Mp = &M1; Sp = &S1; }
      else if (r == 2){ Mp = &M2; Sp = &S2; } else { Mp = &M3; Sp = &S3; }
      if (valid){
        const float Mn = fmaxf(*Mp, v);
        *Sp = *Sp * __expf(*Mp - Mn) + __expf(v - Mn);
        *Mp = Mn;
      }
    }
  }

  #define MERGE_LANES(MV, SV)                          \
  {                                                    \
    _Pragma("unroll")                                  \
    for (int o = 1; o < 16; o <<= 1){                  \
      const float Mo = __shfl_xor((MV), o);            \
      const float So = __shfl_xor((SV), o);            \
      const float Mn = fmaxf((MV), Mo);                \
      (SV) = (SV) * __expf((MV) - Mn) + So * __expf(Mo - Mn); \
      (MV) = Mn;                                       \
    }                                                  \
  }
  MERGE_LANES(M0, S0) MERGE_LANES(M1, S1) MERGE_LANES(M2, S2) MERGE_LANES(M3, S3)
  #undef MERGE_LANES

  if (nloc == 0){
    part[w][kg * 4 + 0] = make_float2(M0, S0);
    part[w][kg * 4 + 1] = make_float2(M1, S1);
    part[w][kg * 4 + 2] = make_float2(M2, S2);
    part[w][kg * 4 + 3] = make_float2(M3, S3);
  }
  __syncthreads();

  if (w == 0 && l < 16){
    const int row = l;
    float Mm = -1e30f, Ss = 0.f;
    #pragma unroll
    for (int j = 0; j < 4; j++){
      const float2 ps = part[j][row];
      const float Mn = fmaxf(Mm, ps.x);
      Ss = Ss * __expf(Mm - Mn) + ps.y * __expf(ps.x - Mn);
      Mm = Mn;
    }
    float term = Mm + __logf(Ss) - lpos[row];
    #pragma unroll
    for (int o = 8; o >= 1; o >>= 1) term += __shfl_xor(term, o);
    if (l == 0) atomicAdd(out, term / (logf(256.0f) * (float)(2 * n)));
  }
}

extern "C" void kernel_launch(void* const* d_in, const int* in_sizes, int n_in,
                              void* d_out, int out_size, void* d_ws, size_t ws_size,
                              hipStream_t stream) {
  const float* x_a = (const float*)d_in[0];
  const float* x_b = (const float*)d_in[1];
  const float* W_a = (const float*)d_in[2];
  const float* b_a = (const float*)d_in[3];
  const float* W_b = (const float*)d_in[4];
  const float* b_b = (const float*)d_in[5];
  const int*   e_ab = (const int*)d_in[6];   // [2,E]: [0]=src(a), [1]=dst(b)
  const int*   e_ba = (const int*)d_in[7];   // [0]=src(b), [1]=dst(a)
  const int E = in_sizes[6] / 2;
  const int N = in_sizes[0] / D;             // 8192

  char* p = (char*)d_ws;
  ushort* xa16    = (ushort*)p;   p += (size_t)N * D * 2;
  ushort* xb16    = (ushort*)p;   p += (size_t)N * D * 2;
  ushort* ctx0a   = (ushort*)p;   p += (size_t)N * D * 2;
  ushort* ctx0b   = (ushort*)p;   p += (size_t)N * D * 2;
  ushort* W16a    = (ushort*)p;   p += (size_t)D * D * 2;
  ushort* W16b    = (ushort*)p;   p += (size_t)D * D * 2;
  int*    gcnt    = (int*)p;      p += (size_t)2 * BK * 4;
  unsigned* scratch = (unsigned*)p; p += (size_t)2 * BK * SCAP * 4;

  prep_kernel<<<16, 256, 0, stream>>>(
      W_a, W_b, W16a, W16b, gcnt, (float*)d_out, N);

  linear_scatter<<<2 * (N / 64) + 512, 256, 0, stream>>>(
      x_a, x_b, W16a, W16b, b_a, b_b, xa16, xb16, ctx0a, ctx0b,
      e_ba, e_ab, gcnt, scratch, E, N);

  loss_fused<<<2 * (N / 16), 256, 0, stream>>>(
      xa16, xb16, ctx0a, ctx0b, gcnt, scratch, (float*)d_out, N);
}